// Round 1
// 7846.765 us; speedup vs baseline: 1.2735x; 1.2735x over previous
//
#include <hip/hip_runtime.h>
#include <math.h>

static constexpr int BATCH = 8;
static constexpr int NFC   = 128;   // NF
static constexpr int IMGS  = 64;    // IMG
static constexpr int PIX   = IMGS * IMGS;      // 4096
static constexpr int FIN   = NFC * 3;          // 384
static constexpr int FH    = NFC;              // 128
static constexpr int FO    = NFC * 2;          // 256
static constexpr int LATD  = 256;
static constexpr int KTOT  = 197376;
static constexpr int NCALLS = 16;

// kall offsets
static constexpr int OFF_WIN  = 0;
static constexpr int OFF_BIN  = 49152;
static constexpr int OFF_WMID = 49280;
static constexpr int OFF_BMID = 65664;
static constexpr int OFF_WOUT = 65792;
static constexpr int OFF_BOUT = 98560;
static constexpr int OFF_WSH  = 98816;
static constexpr int OFF_BSH  = 197120;

// -------------------- hypernetwork: kall = lat @ hyper_w + hyper_b --------------------
__global__ void hyper_kernel(const float* __restrict__ lat, const float* __restrict__ hw,
                             const float* __restrict__ hb, float* __restrict__ kall) {
    __shared__ float lat_s[BATCH * LATD];
    int tid = threadIdx.x;
    for (int i = tid; i < BATCH * LATD; i += 256) lat_s[i] = lat[i];
    __syncthreads();
    int j = blockIdx.x * 256 + tid;
    float acc[BATCH];
#pragma unroll
    for (int b = 0; b < BATCH; b++) acc[b] = 0.f;
#pragma unroll 4
    for (int k = 0; k < LATD; k++) {
        float w = hw[(size_t)k * KTOT + j];
#pragma unroll
        for (int b = 0; b < BATCH; b++) acc[b] += lat_s[b * LATD + k] * w;
    }
    float bias = hb[j];
#pragma unroll
    for (int b = 0; b < BATCH; b++) kall[(size_t)b * KTOT + j] = acc[b] + bias;
}

// -------------------- float4 copy --------------------
__global__ void copy4_kernel(const float4* __restrict__ src, float4* __restrict__ dst, int n4) {
    int i = blockIdx.x * 256 + threadIdx.x;
    if (i < n4) dst[i] = src[i];
}

// -------------------- per-step: sobel dwconv + per-channel norm, writes p (384 ch) ------
__global__ void norm_kernel(const float* __restrict__ state, float* __restrict__ p) {
    __shared__ float buf[PIX];      // 16 KB
    __shared__ float rbuf[12];
    int c = blockIdx.x, b = blockIdx.y;
    const float* src = state + ((size_t)b * NFC + c) * PIX;
    int tid = threadIdx.x;
    for (int i = tid; i < PIX; i += 256) buf[i] = src[i];
    __syncthreads();

    const float S0 = 6.123233995736766e-17f, S1 = 0.70710678118654752f, S2 = 1.0f;
    const float Sv[5] = {S0, S1, S2, S1, S0};
    const float Dv[5] = {-1.0f, -0.70710678118654752f, 0.0f, 0.70710678118654752f, 1.0f};

    float px[16], py[16], v0[16];
#pragma unroll
    for (int i = 0; i < 16; i++) {
        int pix = tid + 256 * i;
        int y = pix >> 6, x = pix & 63;
        float ax = 0.f, ay = 0.f;
#pragma unroll
        for (int t = 0; t < 25; t++) {
            int dy = t / 5 - 2, dx = t % 5 - 2;
            int yy = y + dy, xx = x + dx;
            bool ok = (yy >= 0) && (yy < IMGS) && (xx >= 0) && (xx < IMGS);
            float v = ok ? buf[yy * IMGS + xx] : 0.f;
            ax += Sv[dy + 2] * Dv[dx + 2] * v;
            ay += Dv[dy + 2] * Sv[dx + 2] * v;
        }
        px[i] = ax; py[i] = ay; v0[i] = buf[pix];
    }

    int lane = tid & 63, wv = tid >> 6;
    // pass 1: sums -> means
    float s0 = 0.f, s1 = 0.f, s2 = 0.f;
#pragma unroll
    for (int i = 0; i < 16; i++) { s0 += v0[i]; s1 += px[i]; s2 += py[i]; }
    for (int off = 32; off > 0; off >>= 1) {
        s0 += __shfl_down(s0, off); s1 += __shfl_down(s1, off); s2 += __shfl_down(s2, off);
    }
    if (lane == 0) { rbuf[wv] = s0; rbuf[4 + wv] = s1; rbuf[8 + wv] = s2; }
    __syncthreads();
    float mu0 = (rbuf[0] + rbuf[1] + rbuf[2] + rbuf[3]) * (1.f / PIX);
    float mu1 = (rbuf[4] + rbuf[5] + rbuf[6] + rbuf[7]) * (1.f / PIX);
    float mu2 = (rbuf[8] + rbuf[9] + rbuf[10] + rbuf[11]) * (1.f / PIX);
    __syncthreads();
    // pass 2: variance (two-pass avoids cancellation at |x|~450)
    float q0 = 0.f, q1 = 0.f, q2 = 0.f;
#pragma unroll
    for (int i = 0; i < 16; i++) {
        float d0 = v0[i] - mu0, d1 = px[i] - mu1, d2 = py[i] - mu2;
        q0 += d0 * d0; q1 += d1 * d1; q2 += d2 * d2;
    }
    for (int off = 32; off > 0; off >>= 1) {
        q0 += __shfl_down(q0, off); q1 += __shfl_down(q1, off); q2 += __shfl_down(q2, off);
    }
    if (lane == 0) { rbuf[wv] = q0; rbuf[4 + wv] = q1; rbuf[8 + wv] = q2; }
    __syncthreads();
    float var0 = (rbuf[0] + rbuf[1] + rbuf[2] + rbuf[3]) * (1.f / PIX);
    float var1 = (rbuf[4] + rbuf[5] + rbuf[6] + rbuf[7]) * (1.f / PIX);
    float var2 = (rbuf[8] + rbuf[9] + rbuf[10] + rbuf[11]) * (1.f / PIX);
    float sc0 = rsqrtf(var0 + 1e-5f), sc1 = rsqrtf(var1 + 1e-5f), sc2 = rsqrtf(var2 + 1e-5f);

    float* p0 = p + ((size_t)b * FIN + c) * PIX;
    float* p1 = p + ((size_t)b * FIN + 128 + c) * PIX;
    float* p2 = p + ((size_t)b * FIN + 256 + c) * PIX;
#pragma unroll
    for (int i = 0; i < 16; i++) {
        int pix = tid + 256 * i;
        p0[pix] = (v0[i] - mu0) * sc0;
        p1[pix] = (px[i] - mu1) * sc1;
        p2[pix] = (py[i] - mu2) * sc2;
    }
}

// -------------------- fp32 tiled GEMM: C[M][4096] = act(scale*W @ X + bias) -----------
// W = kall + b*KTOT + woff (row-major [M][K]); bias = kall + b*KTOT + boff
__global__ void gemm_kernel(const float* __restrict__ kall, int woff, int boff,
                            const float* __restrict__ X, float* __restrict__ C,
                            int M, int K, float scale, int act, int accum) {
    __shared__ float Ws[16][68];   // padded: 16B-aligned rows, low conflict
    __shared__ float Xs[16][64];
    int b = blockIdx.z;
    const float* W    = kall + (size_t)b * KTOT + woff;
    const float* bias = kall + (size_t)b * KTOT + boff;
    const float* Xb   = X + (size_t)b * K * PIX;
    float* Cb         = C + (size_t)b * M * PIX;
    int bn = blockIdx.x * 64, bm = blockIdx.y * 64;
    int tid = threadIdx.x, tx = tid & 15, ty = tid >> 4;
    float acc[4][4];
#pragma unroll
    for (int i = 0; i < 4; i++)
#pragma unroll
        for (int j = 0; j < 4; j++) acc[i][j] = 0.f;

    for (int k0 = 0; k0 < K; k0 += 16) {
#pragma unroll
        for (int u = 0; u < 4; u++) {
            int idx = tid + 256 * u;
            int m = idx >> 4, kk = idx & 15;
            Ws[kk][m] = W[(size_t)(bm + m) * K + k0 + kk] * scale;
        }
#pragma unroll
        for (int u = 0; u < 4; u++) {
            int idx = tid + 256 * u;
            int n = idx & 63, kk = idx >> 6;
            Xs[kk][n] = Xb[(size_t)(k0 + kk) * PIX + bn + n];
        }
        __syncthreads();
#pragma unroll
        for (int kk = 0; kk < 16; kk++) {
            float4 av = *(const float4*)&Ws[kk][ty * 4];
            float4 bv = *(const float4*)&Xs[kk][tx * 4];
            acc[0][0] += av.x * bv.x; acc[0][1] += av.x * bv.y; acc[0][2] += av.x * bv.z; acc[0][3] += av.x * bv.w;
            acc[1][0] += av.y * bv.x; acc[1][1] += av.y * bv.y; acc[1][2] += av.y * bv.z; acc[1][3] += av.y * bv.w;
            acc[2][0] += av.z * bv.x; acc[2][1] += av.z * bv.y; acc[2][2] += av.z * bv.z; acc[2][3] += av.z * bv.w;
            acc[3][0] += av.w * bv.x; acc[3][1] += av.w * bv.y; acc[3][2] += av.w * bv.z; acc[3][3] += av.w * bv.w;
        }
        __syncthreads();
    }
#pragma unroll
    for (int i = 0; i < 4; i++) {
        int m = bm + ty * 4 + i;
        float bv = bias[m];
        float4 v = make_float4(acc[i][0] + bv, acc[i][1] + bv, acc[i][2] + bv, acc[i][3] + bv);
        float4* cp = (float4*)&Cb[(size_t)m * PIX + bn + tx * 4];
        if (accum) {
            float4 o = *cp;
            v.x += o.x; v.y += o.y; v.z += o.z; v.w += o.w;
        }
        if (act) {
            v.x = fmaxf(v.x, 0.f); v.y = fmaxf(v.y, 0.f);
            v.z = fmaxf(v.z, 0.f); v.w = fmaxf(v.w, 0.f);
        }
        *cp = v;
    }
}

// -------------------- 3x3 conv 128->128 as implicit GEMM --------------------
// C[oc][pix] = sum_{k=ic*9+tap} W[oc][k] * X[k][pix_shifted(tap)]
// W = res_w* row-major [oc][ic][3][3] == [oc][K=1152] exactly.
// Each blockIdx.x handles one image row (64 consecutive pixels): bn = y*64.
// X staged into LDS on the fly: tap-shifted coalesced row loads, zero-padded.
__global__ void conv_gemm_kernel(const float* __restrict__ in, const float* __restrict__ W,
                                 const float* __restrict__ bias, const float* __restrict__ resid,
                                 float* __restrict__ outp, int relu) {
    __shared__ float Ws[16][68];
    __shared__ float Xs[16][64];
    constexpr int K = NFC * 9;   // 1152
    int b = blockIdx.z;
    int y  = blockIdx.x;         // image row; pixels [y*64, y*64+63]
    int bn = y * IMGS, bm = blockIdx.y * 64;
    int tid = threadIdx.x, tx = tid & 15, ty = tid >> 4;
    const float* inb = in + (size_t)b * NFC * PIX;
    float acc[4][4];
#pragma unroll
    for (int i = 0; i < 4; i++)
#pragma unroll
        for (int j = 0; j < 4; j++) acc[i][j] = 0.f;

    for (int k0 = 0; k0 < K; k0 += 16) {
#pragma unroll
        for (int u = 0; u < 4; u++) {
            int idx = tid + 256 * u;
            int m = idx >> 4, kk = idx & 15;
            Ws[kk][m] = W[(size_t)(bm + m) * K + k0 + kk];
        }
#pragma unroll
        for (int u = 0; u < 4; u++) {
            int idx = tid + 256 * u;
            int n = idx & 63, kk = idx >> 6;
            int k = k0 + kk;
            int ic = k / 9;
            int t  = k - ic * 9;
            int dy = t / 3 - 1;
            int dx = t - (t / 3) * 3 - 1;
            int yy = y + dy, xx = n + dx;
            float v = 0.f;
            if (yy >= 0 && yy < IMGS && xx >= 0 && xx < IMGS)
                v = inb[((size_t)ic * IMGS + yy) * IMGS + xx];
            Xs[kk][n] = v;
        }
        __syncthreads();
#pragma unroll
        for (int kk = 0; kk < 16; kk++) {
            float4 av = *(const float4*)&Ws[kk][ty * 4];
            float4 bv = *(const float4*)&Xs[kk][tx * 4];
            acc[0][0] += av.x * bv.x; acc[0][1] += av.x * bv.y; acc[0][2] += av.x * bv.z; acc[0][3] += av.x * bv.w;
            acc[1][0] += av.y * bv.x; acc[1][1] += av.y * bv.y; acc[1][2] += av.y * bv.z; acc[1][3] += av.y * bv.w;
            acc[2][0] += av.z * bv.x; acc[2][1] += av.z * bv.y; acc[2][2] += av.z * bv.z; acc[2][3] += av.z * bv.w;
            acc[3][0] += av.w * bv.x; acc[3][1] += av.w * bv.y; acc[3][2] += av.w * bv.z; acc[3][3] += av.w * bv.w;
        }
        __syncthreads();
    }
#pragma unroll
    for (int i = 0; i < 4; i++) {
        int m = bm + ty * 4 + i;
        float bv = bias[m];
        float4 v = make_float4(acc[i][0] + bv, acc[i][1] + bv, acc[i][2] + bv, acc[i][3] + bv);
        size_t off = ((size_t)b * NFC + m) * PIX + bn + tx * 4;
        if (resid) {
            float4 o = *(const float4*)&resid[off];
            v.x += o.x; v.y += o.y; v.z += o.z; v.w += o.w;
        }
        if (relu) {
            v.x = fmaxf(v.x, 0.f); v.y = fmaxf(v.y, 0.f);
            v.z = fmaxf(v.z, 0.f); v.w = fmaxf(v.w, 0.f);
        }
        *(float4*)&outp[off] = v;
    }
}

// -------------------- gating + leaky update --------------------
__global__ void gate_kernel(const float* __restrict__ dn, const float* __restrict__ oldS,
                            float* __restrict__ newS, const float* __restrict__ leak_p) {
    float leak = fminf(fmaxf(leak_p[0], 0.001f), 1000.f);
    int i = blockIdx.x * 256 + threadIdx.x;   // over B*NF*PIX = 4194304
    int b = i >> 19;                          // / (NF*PIX)
    int r = i & (NFC * PIX - 1);
    float val  = dn[(size_t)b * FO * PIX + r];
    float gate = dn[(size_t)b * FO * PIX + NFC * PIX + r];
    float sg = 1.f / (1.f + expf(-gate));
    newS[i] = oldS[i] + leak * val * sg;
}

// -------------------- final 3-channel image conv + clip --------------------
__global__ void img_kernel(const float* __restrict__ y, const float* __restrict__ W,
                           const float* __restrict__ bias, float* __restrict__ oimg,
                           float* __restrict__ oraw) {
    int b = blockIdx.y;
    int pix = blockIdx.x * 256 + threadIdx.x;
    int yy0 = pix >> 6, xx0 = pix & 63;
    float acc[3] = {bias[0], bias[1], bias[2]};
    for (int c = 0; c < NFC; c++) {
        const float* yp = y + ((size_t)b * NFC + c) * PIX;
#pragma unroll
        for (int tap = 0; tap < 9; tap++) {
            int dy = tap / 3 - 1, dx = tap % 3 - 1;
            int yy = yy0 + dy, xx = xx0 + dx;
            float v = (yy >= 0 && yy < IMGS && xx >= 0 && xx < IMGS) ? yp[yy * IMGS + xx] : 0.f;
#pragma unroll
            for (int o = 0; o < 3; o++) acc[o] += W[((size_t)o * NFC + c) * 9 + tap] * v;
        }
    }
#pragma unroll
    for (int o = 0; o < 3; o++) {
        size_t off = ((size_t)b * 3 + o) * PIX + pix;
        oraw[off] = acc[o];
        oimg[off] = fminf(fmaxf(acc[o], -1.f), 1.f);
    }
}

extern "C" void kernel_launch(void* const* d_in, const int* in_sizes, int n_in,
                              void* d_out, int out_size, void* d_ws, size_t ws_size,
                              hipStream_t stream) {
    const float* lat     = (const float*)d_in[0];
    const float* ca_init = (const float*)d_in[1];
    const float* leak    = (const float*)d_in[2];
    const float* hyper_w = (const float*)d_in[3];
    const float* hyper_b = (const float*)d_in[4];
    const float* res_w1  = (const float*)d_in[5];
    const float* res_b1  = (const float*)d_in[6];
    const float* res_w2  = (const float*)d_in[7];
    const float* res_b2  = (const float*)d_in[8];
    const float* img_w   = (const float*)d_in[9];
    const float* img_b   = (const float*)d_in[10];

    float* out      = (float*)d_out;
    float* out_img  = out;
    float* embs     = out + (size_t)BATCH * 3 * PIX;                  // 98304
    float* out_raw  = embs + (size_t)(NCALLS + 1) * BATCH * NFC * PIX;

    float* ws   = (float*)d_ws;
    float* kall = ws;
    float* p    = kall + (size_t)BATCH * KTOT;        // 1,579,008
    float* h1   = p  + (size_t)BATCH * FIN * PIX;     // +12,582,912
    float* h2   = h1 + (size_t)BATCH * NFC * PIX;     // +4,194,304
    float* dn   = h2 + (size_t)BATCH * NFC * PIX;     // +4,194,304 (dn: 8,388,608)
    float* hres = h1;   // reused after the step loop
    float* ybuf = h2;

    const float rsq384 = 0.051031036307982884f;  // 1/sqrt(384)
    const float rsq128 = 0.088388347648318447f;  // 1/sqrt(128)

    hyper_kernel<<<KTOT / 256, 256, 0, stream>>>(lat, hyper_w, hyper_b, kall);

    int n4 = BATCH * NFC * PIX / 4;
    copy4_kernel<<<(n4 + 255) / 256, 256, 0, stream>>>((const float4*)ca_init, (float4*)embs, n4);

    const size_t stateN = (size_t)BATCH * NFC * PIX;
    for (int t = 0; t < NCALLS; t++) {
        const float* cur = embs + (size_t)t * stateN;
        float* nxt = embs + (size_t)(t + 1) * stateN;
        norm_kernel<<<dim3(NFC, BATCH), 256, 0, stream>>>(cur, p);
        gemm_kernel<<<dim3(64, FH / 64, BATCH), 256, 0, stream>>>(kall, OFF_WIN,  OFF_BIN,  p,  h1, FH, FIN, rsq384, 1, 0);
        gemm_kernel<<<dim3(64, FH / 64, BATCH), 256, 0, stream>>>(kall, OFF_WMID, OFF_BMID, h1, h2, FH, FH,  rsq128, 1, 0);
        gemm_kernel<<<dim3(64, FO / 64, BATCH), 256, 0, stream>>>(kall, OFF_WOUT, OFF_BOUT, h2, dn, FO, FH,  rsq128, 0, 0);
        gemm_kernel<<<dim3(64, FO / 64, BATCH), 256, 0, stream>>>(kall, OFF_WSH,  OFF_BSH,  p,  dn, FO, FIN, rsq384, 0, 1);
        gate_kernel<<<(int)(stateN / 256), 256, 0, stream>>>(dn, cur, nxt, leak);
    }

    const float* fin = embs + (size_t)NCALLS * stateN;
    conv_gemm_kernel<<<dim3(64, 2, BATCH), 256, 0, stream>>>(fin,  res_w1, res_b1, nullptr, hres, 1);
    conv_gemm_kernel<<<dim3(64, 2, BATCH), 256, 0, stream>>>(hres, res_w2, res_b2, fin,     ybuf, 0);
    img_kernel<<<dim3(16, BATCH), 256, 0, stream>>>(ybuf, img_w, img_b, out_img, out_raw);
}

// Round 3
// 4149.899 us; speedup vs baseline: 2.4079x; 1.8908x over previous
//
#include <hip/hip_runtime.h>
#include <math.h>

static constexpr int BATCH = 8;
static constexpr int NFC   = 128;   // NF
static constexpr int IMGS  = 64;    // IMG
static constexpr int PIX   = IMGS * IMGS;      // 4096
static constexpr int FIN   = NFC * 3;          // 384
static constexpr int FH    = NFC;              // 128
static constexpr int FO    = NFC * 2;          // 256
static constexpr int LATD  = 256;
static constexpr int KTOT  = 197376;
static constexpr int NCALLS = 16;

// kall offsets
static constexpr int OFF_WIN  = 0;
static constexpr int OFF_BIN  = 49152;
static constexpr int OFF_WMID = 49280;
static constexpr int OFF_BMID = 65664;
static constexpr int OFF_WOUT = 65792;
static constexpr int OFF_BOUT = 98560;
static constexpr int OFF_WSH  = 98816;
static constexpr int OFF_BSH  = 197120;

static constexpr float RSQ384 = 0.051031036307982884f;  // 1/sqrt(384)
static constexpr float RSQ128 = 0.088388347648318447f;  // 1/sqrt(128)

// -------------------- hypernetwork: kall = lat @ hyper_w + hyper_b --------------------
__global__ void hyper_kernel(const float* __restrict__ lat, const float* __restrict__ hw,
                             const float* __restrict__ hb, float* __restrict__ kall) {
    __shared__ float lat_s[BATCH * LATD];
    int tid = threadIdx.x;
    for (int i = tid; i < BATCH * LATD; i += 256) lat_s[i] = lat[i];
    __syncthreads();
    int j = blockIdx.x * 256 + tid;
    float acc[BATCH];
#pragma unroll
    for (int b = 0; b < BATCH; b++) acc[b] = 0.f;
#pragma unroll 4
    for (int k = 0; k < LATD; k++) {
        float w = hw[(size_t)k * KTOT + j];
#pragma unroll
        for (int b = 0; b < BATCH; b++) acc[b] += lat_s[b * LATD + k] * w;
    }
    float bias = hb[j];
#pragma unroll
    for (int b = 0; b < BATCH; b++) kall[(size_t)b * KTOT + j] = acc[b] + bias;
}

// -------------------- float4 copy --------------------
__global__ void copy4_kernel(const float4* __restrict__ src, float4* __restrict__ dst, int n4) {
    int i = blockIdx.x * 256 + threadIdx.x;
    if (i < n4) dst[i] = src[i];
}

// -------------------- per-step: separable sobel dwconv + per-channel norm ------
// One block per (channel, batch). Each thread owns 4 groups of 4 CONSECUTIVE pixels
// (pix = 4*tid + 1024*g) so all global IO is float4.
__global__ void norm_kernel(const float* __restrict__ state, float* __restrict__ p) {
    __shared__ float buf[PIX];      // 16 KB raw channel
    __shared__ float t0s[PIX];      // 16 KB column-pass (Sv) for kx
    __shared__ float t1s[PIX];      // 16 KB column-pass (Dv) for ky
    __shared__ float rbuf[12];
    int c = blockIdx.x, b = blockIdx.y;
    int tid = threadIdx.x;
    const float4* src4 = (const float4*)(state + ((size_t)b * NFC + c) * PIX);
    float4* buf4 = (float4*)buf;
    for (int i = tid; i < PIX / 4; i += 256) buf4[i] = src4[i];
    __syncthreads();

    const float S1 = 0.70710678118654752f;
    const float Sv[5] = {6.123233995736766e-17f, S1, 1.0f, S1, 6.123233995736766e-17f};
    const float Dv[5] = {-1.0f, -S1, 0.0f, S1, 1.0f};

    int base = tid * 4;
    int x0 = base & 63;        // multiple of 4
    int y0 = base >> 6;        // 0..15
    int q  = x0 >> 2;          // float4 column index

    float4 v0r[4], pxr[4], pyr[4];

    // column pass -> t0s/t1s (separable: kx = Sv(col) x Dv(row-of-x), ky = Dv x Sv)
    {
        float4 t0r[4], t1r[4];
#pragma unroll
        for (int g = 0; g < 4; g++) {
            int y = y0 + 16 * g;
            float4 a0 = make_float4(0.f, 0.f, 0.f, 0.f);
            float4 a1 = make_float4(0.f, 0.f, 0.f, 0.f);
#pragma unroll
            for (int dy = -2; dy <= 2; dy++) {
                int yy = y + dy;
                if (yy >= 0 && yy < IMGS) {
                    float4 v = buf4[yy * 16 + q];
                    float sv = Sv[dy + 2], dv = Dv[dy + 2];
                    a0.x += sv * v.x; a0.y += sv * v.y; a0.z += sv * v.z; a0.w += sv * v.w;
                    a1.x += dv * v.x; a1.y += dv * v.y; a1.z += dv * v.z; a1.w += dv * v.w;
                }
            }
            t0r[g] = a0; t1r[g] = a1;
            v0r[g] = buf4[y * 16 + q];
        }
#pragma unroll
        for (int g = 0; g < 4; g++) {
            int y = y0 + 16 * g;
            ((float4*)t0s)[y * 16 + q] = t0r[g];
            ((float4*)t1s)[y * 16 + q] = t1r[g];
        }
    }
    __syncthreads();

    // row pass: px = sum_dx Dv[dx]*t0(y, x+dx);  py = sum_dx Sv[dx]*t1(y, x+dx)
#pragma unroll
    for (int g = 0; g < 4; g++) {
        int y = y0 + 16 * g;
        float A0[8], A1[8];
#pragma unroll
        for (int k = 0; k < 8; k++) {
            int x = x0 - 2 + k;
            bool ok = (x >= 0) && (x < IMGS);
            A0[k] = ok ? t0s[y * IMGS + x] : 0.f;
            A1[k] = ok ? t1s[y * IMGS + x] : 0.f;
        }
        float px_[4], py_[4];
#pragma unroll
        for (int j = 0; j < 4; j++) {
            float ax = 0.f, ay = 0.f;
#pragma unroll
            for (int d = 0; d < 5; d++) {
                ax += Dv[d] * A0[j + d];
                ay += Sv[d] * A1[j + d];
            }
            px_[j] = ax; py_[j] = ay;
        }
        pxr[g] = make_float4(px_[0], px_[1], px_[2], px_[3]);
        pyr[g] = make_float4(py_[0], py_[1], py_[2], py_[3]);
    }

    int lane = tid & 63, wv = tid >> 6;
    // pass 1: sums -> means
    float s0 = 0.f, s1 = 0.f, s2 = 0.f;
#pragma unroll
    for (int g = 0; g < 4; g++) {
        s0 += v0r[g].x + v0r[g].y + v0r[g].z + v0r[g].w;
        s1 += pxr[g].x + pxr[g].y + pxr[g].z + pxr[g].w;
        s2 += pyr[g].x + pyr[g].y + pyr[g].z + pyr[g].w;
    }
    for (int off = 32; off > 0; off >>= 1) {
        s0 += __shfl_down(s0, off); s1 += __shfl_down(s1, off); s2 += __shfl_down(s2, off);
    }
    if (lane == 0) { rbuf[wv] = s0; rbuf[4 + wv] = s1; rbuf[8 + wv] = s2; }
    __syncthreads();
    float mu0 = (rbuf[0] + rbuf[1] + rbuf[2] + rbuf[3]) * (1.f / PIX);
    float mu1 = (rbuf[4] + rbuf[5] + rbuf[6] + rbuf[7]) * (1.f / PIX);
    float mu2 = (rbuf[8] + rbuf[9] + rbuf[10] + rbuf[11]) * (1.f / PIX);
    __syncthreads();
    // pass 2: variance (two-pass avoids cancellation)
    float q0 = 0.f, q1 = 0.f, q2 = 0.f;
#pragma unroll
    for (int g = 0; g < 4; g++) {
        float d;
        d = v0r[g].x - mu0; q0 += d * d;  d = v0r[g].y - mu0; q0 += d * d;
        d = v0r[g].z - mu0; q0 += d * d;  d = v0r[g].w - mu0; q0 += d * d;
        d = pxr[g].x - mu1; q1 += d * d;  d = pxr[g].y - mu1; q1 += d * d;
        d = pxr[g].z - mu1; q1 += d * d;  d = pxr[g].w - mu1; q1 += d * d;
        d = pyr[g].x - mu2; q2 += d * d;  d = pyr[g].y - mu2; q2 += d * d;
        d = pyr[g].z - mu2; q2 += d * d;  d = pyr[g].w - mu2; q2 += d * d;
    }
    for (int off = 32; off > 0; off >>= 1) {
        q0 += __shfl_down(q0, off); q1 += __shfl_down(q1, off); q2 += __shfl_down(q2, off);
    }
    if (lane == 0) { rbuf[wv] = q0; rbuf[4 + wv] = q1; rbuf[8 + wv] = q2; }
    __syncthreads();
    float var0 = (rbuf[0] + rbuf[1] + rbuf[2] + rbuf[3]) * (1.f / PIX);
    float var1 = (rbuf[4] + rbuf[5] + rbuf[6] + rbuf[7]) * (1.f / PIX);
    float var2 = (rbuf[8] + rbuf[9] + rbuf[10] + rbuf[11]) * (1.f / PIX);
    float sc0 = rsqrtf(var0 + 1e-5f), sc1 = rsqrtf(var1 + 1e-5f), sc2 = rsqrtf(var2 + 1e-5f);

    float4* p0 = (float4*)(p + ((size_t)b * FIN + c) * PIX);
    float4* p1 = (float4*)(p + ((size_t)b * FIN + 128 + c) * PIX);
    float4* p2 = (float4*)(p + ((size_t)b * FIN + 256 + c) * PIX);
#pragma unroll
    for (int g = 0; g < 4; g++) {
        int i4 = tid + 256 * g;
        float4 o;
        o.x = (v0r[g].x - mu0) * sc0; o.y = (v0r[g].y - mu0) * sc0;
        o.z = (v0r[g].z - mu0) * sc0; o.w = (v0r[g].w - mu0) * sc0;
        p0[i4] = o;
        o.x = (pxr[g].x - mu1) * sc1; o.y = (pxr[g].y - mu1) * sc1;
        o.z = (pxr[g].z - mu1) * sc1; o.w = (pxr[g].w - mu1) * sc1;
        p1[i4] = o;
        o.x = (pyr[g].x - mu2) * sc2; o.y = (pyr[g].y - mu2) * sc2;
        o.z = (pyr[g].z - mu2) * sc2; o.w = (pyr[g].w - mu2) * sc2;
        p2[i4] = o;
    }
}

// -------------------- fused h2 = relu(Wmid @ relu(Win @ p + bin) + bmid) --------------
// Block: full M=128, one 64-px column tile. h1 lives only in LDS.
__global__ void fused_h_kernel(const float* __restrict__ kall, const float* __restrict__ p,
                               float* __restrict__ h2) {
    __shared__ float Wa[16][68];
    __shared__ float Wb[16][68];
    __shared__ float Xs[16][64];
    __shared__ float h1s[128][64];   // 32 KB
    int b = blockIdx.y;
    int bn = blockIdx.x * 64;
    int tid = threadIdx.x, tx = tid & 15, ty = tid >> 4;
    const float* Win  = kall + (size_t)b * KTOT + OFF_WIN;
    const float* bin  = kall + (size_t)b * KTOT + OFF_BIN;
    const float* Wmid = kall + (size_t)b * KTOT + OFF_WMID;
    const float* bmid = kall + (size_t)b * KTOT + OFF_BMID;
    const float* Xb   = p + (size_t)b * FIN * PIX;
    float acc1[4][4], acc2[4][4];
#pragma unroll
    for (int i = 0; i < 4; i++)
#pragma unroll
        for (int j = 0; j < 4; j++) { acc1[i][j] = 0.f; acc2[i][j] = 0.f; }

    // ---- GEMM 1: h1 = Win @ p (K = 384) ----
    for (int k0 = 0; k0 < FIN; k0 += 16) {
#pragma unroll
        for (int u = 0; u < 4; u++) {
            int idx = tid + 256 * u;
            int m = idx >> 4, kk = idx & 15;
            Wa[kk][m] = Win[(size_t)m * FIN + k0 + kk] * RSQ384;
            Wb[kk][m] = Win[(size_t)(64 + m) * FIN + k0 + kk] * RSQ384;
        }
#pragma unroll
        for (int u = 0; u < 4; u++) {
            int idx = tid + 256 * u;
            int n = idx & 63, kk = idx >> 6;
            Xs[kk][n] = Xb[(size_t)(k0 + kk) * PIX + bn + n];
        }
        __syncthreads();
#pragma unroll
        for (int kk = 0; kk < 16; kk++) {
            float4 xv = *(const float4*)&Xs[kk][tx * 4];
            float4 wa = *(const float4*)&Wa[kk][ty * 4];
            float4 wb = *(const float4*)&Wb[kk][ty * 4];
            acc1[0][0] += wa.x * xv.x; acc1[0][1] += wa.x * xv.y; acc1[0][2] += wa.x * xv.z; acc1[0][3] += wa.x * xv.w;
            acc1[1][0] += wa.y * xv.x; acc1[1][1] += wa.y * xv.y; acc1[1][2] += wa.y * xv.z; acc1[1][3] += wa.y * xv.w;
            acc1[2][0] += wa.z * xv.x; acc1[2][1] += wa.z * xv.y; acc1[2][2] += wa.z * xv.z; acc1[2][3] += wa.z * xv.w;
            acc1[3][0] += wa.w * xv.x; acc1[3][1] += wa.w * xv.y; acc1[3][2] += wa.w * xv.z; acc1[3][3] += wa.w * xv.w;
            acc2[0][0] += wb.x * xv.x; acc2[0][1] += wb.x * xv.y; acc2[0][2] += wb.x * xv.z; acc2[0][3] += wb.x * xv.w;
            acc2[1][0] += wb.y * xv.x; acc2[1][1] += wb.y * xv.y; acc2[1][2] += wb.y * xv.z; acc2[1][3] += wb.y * xv.w;
            acc2[2][0] += wb.z * xv.x; acc2[2][1] += wb.z * xv.y; acc2[2][2] += wb.z * xv.z; acc2[2][3] += wb.z * xv.w;
            acc2[3][0] += wb.w * xv.x; acc2[3][1] += wb.w * xv.y; acc2[3][2] += wb.w * xv.z; acc2[3][3] += wb.w * xv.w;
        }
        __syncthreads();
    }
    // relu + bias -> h1s; reset acc
#pragma unroll
    for (int i = 0; i < 4; i++) {
        int m = ty * 4 + i;
        float b1 = bin[m], b2 = bin[64 + m];
        float4 v1 = make_float4(fmaxf(acc1[i][0] + b1, 0.f), fmaxf(acc1[i][1] + b1, 0.f),
                                fmaxf(acc1[i][2] + b1, 0.f), fmaxf(acc1[i][3] + b1, 0.f));
        float4 v2 = make_float4(fmaxf(acc2[i][0] + b2, 0.f), fmaxf(acc2[i][1] + b2, 0.f),
                                fmaxf(acc2[i][2] + b2, 0.f), fmaxf(acc2[i][3] + b2, 0.f));
        *(float4*)&h1s[m][tx * 4] = v1;
        *(float4*)&h1s[64 + m][tx * 4] = v2;
#pragma unroll
        for (int j = 0; j < 4; j++) { acc1[i][j] = 0.f; acc2[i][j] = 0.f; }
    }

    // ---- GEMM 2: h2 = Wmid @ h1 (K = 128), X from LDS ----
    for (int k0 = 0; k0 < FH; k0 += 16) {
#pragma unroll
        for (int u = 0; u < 4; u++) {
            int idx = tid + 256 * u;
            int m = idx >> 4, kk = idx & 15;
            Wa[kk][m] = Wmid[(size_t)m * FH + k0 + kk] * RSQ128;
            Wb[kk][m] = Wmid[(size_t)(64 + m) * FH + k0 + kk] * RSQ128;
        }
        __syncthreads();   // also covers h1s writes on first iteration
#pragma unroll
        for (int kk = 0; kk < 16; kk++) {
            float4 xv = *(const float4*)&h1s[k0 + kk][tx * 4];
            float4 wa = *(const float4*)&Wa[kk][ty * 4];
            float4 wb = *(const float4*)&Wb[kk][ty * 4];
            acc1[0][0] += wa.x * xv.x; acc1[0][1] += wa.x * xv.y; acc1[0][2] += wa.x * xv.z; acc1[0][3] += wa.x * xv.w;
            acc1[1][0] += wa.y * xv.x; acc1[1][1] += wa.y * xv.y; acc1[1][2] += wa.y * xv.z; acc1[1][3] += wa.y * xv.w;
            acc1[2][0] += wa.z * xv.x; acc1[2][1] += wa.z * xv.y; acc1[2][2] += wa.z * xv.z; acc1[2][3] += wa.z * xv.w;
            acc1[3][0] += wa.w * xv.x; acc1[3][1] += wa.w * xv.y; acc1[3][2] += wa.w * xv.z; acc1[3][3] += wa.w * xv.w;
            acc2[0][0] += wb.x * xv.x; acc2[0][1] += wb.x * xv.y; acc2[0][2] += wb.x * xv.z; acc2[0][3] += wb.x * xv.w;
            acc2[1][0] += wb.y * xv.x; acc2[1][1] += wb.y * xv.y; acc2[1][2] += wb.y * xv.z; acc2[1][3] += wb.y * xv.w;
            acc2[2][0] += wb.z * xv.x; acc2[2][1] += wb.z * xv.y; acc2[2][2] += wb.z * xv.z; acc2[2][3] += wb.z * xv.w;
            acc2[3][0] += wb.w * xv.x; acc2[3][1] += wb.w * xv.y; acc2[3][2] += wb.w * xv.z; acc2[3][3] += wb.w * xv.w;
        }
        __syncthreads();
    }
    float* h2b = h2 + (size_t)b * NFC * PIX;
#pragma unroll
    for (int i = 0; i < 4; i++) {
        int m = ty * 4 + i;
        float b1 = bmid[m], b2 = bmid[64 + m];
        float4 v1 = make_float4(fmaxf(acc1[i][0] + b1, 0.f), fmaxf(acc1[i][1] + b1, 0.f),
                                fmaxf(acc1[i][2] + b1, 0.f), fmaxf(acc1[i][3] + b1, 0.f));
        float4 v2 = make_float4(fmaxf(acc2[i][0] + b2, 0.f), fmaxf(acc2[i][1] + b2, 0.f),
                                fmaxf(acc2[i][2] + b2, 0.f), fmaxf(acc2[i][3] + b2, 0.f));
        *(float4*)&h2b[(size_t)m * PIX + bn + tx * 4] = v1;
        *(float4*)&h2b[(size_t)(64 + m) * PIX + bn + tx * 4] = v2;
    }
}

// -------------------- fused dn = Wout@h2 + Wsh@p + biases; gate; state update ----------
// blockIdx.y selects a 64-row val tile (mv) and the matching gate tile (mv+128).
__global__ void fused_dn_kernel(const float* __restrict__ kall, const float* __restrict__ h2,
                                const float* __restrict__ p, const float* __restrict__ cur,
                                float* __restrict__ nxt, const float* __restrict__ leak_p) {
    __shared__ float Wv[16][68];
    __shared__ float Wg[16][68];
    __shared__ float Xs[16][64];
    int b = blockIdx.z;
    int mv = blockIdx.y * 64, mg = 128 + mv;
    int bn = blockIdx.x * 64;
    int tid = threadIdx.x, tx = tid & 15, ty = tid >> 4;
    const float* Wout = kall + (size_t)b * KTOT + OFF_WOUT;   // [256][128]
    const float* Wsh  = kall + (size_t)b * KTOT + OFF_WSH;    // [256][384]
    float accv[4][4], accg[4][4];
#pragma unroll
    for (int i = 0; i < 4; i++)
#pragma unroll
        for (int j = 0; j < 4; j++) { accv[i][j] = 0.f; accg[i][j] = 0.f; }

    // ---- phase 1: += Wout @ h2 (K = 128) ----
    const float* X1 = h2 + (size_t)b * NFC * PIX;
    for (int k0 = 0; k0 < FH; k0 += 16) {
#pragma unroll
        for (int u = 0; u < 4; u++) {
            int idx = tid + 256 * u;
            int m = idx >> 4, kk = idx & 15;
            Wv[kk][m] = Wout[(size_t)(mv + m) * FH + k0 + kk] * RSQ128;
            Wg[kk][m] = Wout[(size_t)(mg + m) * FH + k0 + kk] * RSQ128;
        }
#pragma unroll
        for (int u = 0; u < 4; u++) {
            int idx = tid + 256 * u;
            int n = idx & 63, kk = idx >> 6;
            Xs[kk][n] = X1[(size_t)(k0 + kk) * PIX + bn + n];
        }
        __syncthreads();
#pragma unroll
        for (int kk = 0; kk < 16; kk++) {
            float4 xv = *(const float4*)&Xs[kk][tx * 4];
            float4 wa = *(const float4*)&Wv[kk][ty * 4];
            float4 wb = *(const float4*)&Wg[kk][ty * 4];
            accv[0][0] += wa.x * xv.x; accv[0][1] += wa.x * xv.y; accv[0][2] += wa.x * xv.z; accv[0][3] += wa.x * xv.w;
            accv[1][0] += wa.y * xv.x; accv[1][1] += wa.y * xv.y; accv[1][2] += wa.y * xv.z; accv[1][3] += wa.y * xv.w;
            accv[2][0] += wa.z * xv.x; accv[2][1] += wa.z * xv.y; accv[2][2] += wa.z * xv.z; accv[2][3] += wa.z * xv.w;
            accv[3][0] += wa.w * xv.x; accv[3][1] += wa.w * xv.y; accv[3][2] += wa.w * xv.z; accv[3][3] += wa.w * xv.w;
            accg[0][0] += wb.x * xv.x; accg[0][1] += wb.x * xv.y; accg[0][2] += wb.x * xv.z; accg[0][3] += wb.x * xv.w;
            accg[1][0] += wb.y * xv.x; accg[1][1] += wb.y * xv.y; accg[1][2] += wb.y * xv.z; accg[1][3] += wb.y * xv.w;
            accg[2][0] += wb.z * xv.x; accg[2][1] += wb.z * xv.y; accg[2][2] += wb.z * xv.z; accg[2][3] += wb.z * xv.w;
            accg[3][0] += wb.w * xv.x; accg[3][1] += wb.w * xv.y; accg[3][2] += wb.w * xv.z; accg[3][3] += wb.w * xv.w;
        }
        __syncthreads();
    }
    // ---- phase 2: += Wsh @ p (K = 384) ----
    const float* X2 = p + (size_t)b * FIN * PIX;
    for (int k0 = 0; k0 < FIN; k0 += 16) {
#pragma unroll
        for (int u = 0; u < 4; u++) {
            int idx = tid + 256 * u;
            int m = idx >> 4, kk = idx & 15;
            Wv[kk][m] = Wsh[(size_t)(mv + m) * FIN + k0 + kk] * RSQ384;
            Wg[kk][m] = Wsh[(size_t)(mg + m) * FIN + k0 + kk] * RSQ384;
        }
#pragma unroll
        for (int u = 0; u < 4; u++) {
            int idx = tid + 256 * u;
            int n = idx & 63, kk = idx >> 6;
            Xs[kk][n] = X2[(size_t)(k0 + kk) * PIX + bn + n];
        }
        __syncthreads();
#pragma unroll
        for (int kk = 0; kk < 16; kk++) {
            float4 xv = *(const float4*)&Xs[kk][tx * 4];
            float4 wa = *(const float4*)&Wv[kk][ty * 4];
            float4 wb = *(const float4*)&Wg[kk][ty * 4];
            accv[0][0] += wa.x * xv.x; accv[0][1] += wa.x * xv.y; accv[0][2] += wa.x * xv.z; accv[0][3] += wa.x * xv.w;
            accv[1][0] += wa.y * xv.x; accv[1][1] += wa.y * xv.y; accv[1][2] += wa.y * xv.z; accv[1][3] += wa.y * xv.w;
            accv[2][0] += wa.z * xv.x; accv[2][1] += wa.z * xv.y; accv[2][2] += wa.z * xv.z; accv[2][3] += wa.z * xv.w;
            accv[3][0] += wa.w * xv.x; accv[3][1] += wa.w * xv.y; accv[3][2] += wa.w * xv.z; accv[3][3] += wa.w * xv.w;
            accg[0][0] += wb.x * xv.x; accg[0][1] += wb.x * xv.y; accg[0][2] += wb.x * xv.z; accg[0][3] += wb.x * xv.w;
            accg[1][0] += wb.y * xv.x; accg[1][1] += wb.y * xv.y; accg[1][2] += wb.y * xv.z; accg[1][3] += wb.y * xv.w;
            accg[2][0] += wb.z * xv.x; accg[2][1] += wb.z * xv.y; accg[2][2] += wb.z * xv.z; accg[2][3] += wb.z * xv.w;
            accg[3][0] += wb.w * xv.x; accg[3][1] += wb.w * xv.y; accg[3][2] += wb.w * xv.z; accg[3][3] += wb.w * xv.w;
        }
        __syncthreads();
    }
    // ---- epilogue: dn -> gate -> state update ----
    float leak = fminf(fmaxf(leak_p[0], 0.001f), 1000.f);
    const float* bout = kall + (size_t)b * KTOT + OFF_BOUT;
    const float* bsh  = kall + (size_t)b * KTOT + OFF_BSH;
#pragma unroll
    for (int i = 0; i < 4; i++) {
        int m = ty * 4 + i;
        float bv = bout[mv + m] + bsh[mv + m];
        float bg = bout[mg + m] + bsh[mg + m];
        float4 dv = make_float4(accv[i][0] + bv, accv[i][1] + bv, accv[i][2] + bv, accv[i][3] + bv);
        float4 dg = make_float4(accg[i][0] + bg, accg[i][1] + bg, accg[i][2] + bg, accg[i][3] + bg);
        float4 sg;
        sg.x = 1.f / (1.f + expf(-dg.x)); sg.y = 1.f / (1.f + expf(-dg.y));
        sg.z = 1.f / (1.f + expf(-dg.z)); sg.w = 1.f / (1.f + expf(-dg.w));
        size_t off = ((size_t)b * NFC + mv + m) * PIX + bn + tx * 4;
        float4 cu = *(const float4*)&cur[off];
        float4 o;
        o.x = cu.x + leak * dv.x * sg.x;
        o.y = cu.y + leak * dv.y * sg.y;
        o.z = cu.z + leak * dv.z * sg.z;
        o.w = cu.w + leak * dv.w * sg.w;
        *(float4*)&nxt[off] = o;
    }
}

// -------------------- 3x3 conv 128->128 as implicit GEMM --------------------
__global__ void conv_gemm_kernel(const float* __restrict__ in, const float* __restrict__ W,
                                 const float* __restrict__ bias, const float* __restrict__ resid,
                                 float* __restrict__ outp, int relu) {
    __shared__ float Ws[16][68];
    __shared__ float Xs[16][64];
    constexpr int K = NFC * 9;   // 1152
    int b = blockIdx.z;
    int y  = blockIdx.x;         // image row; pixels [y*64, y*64+63]
    int bn = y * IMGS, bm = blockIdx.y * 64;
    int tid = threadIdx.x, tx = tid & 15, ty = tid >> 4;
    const float* inb = in + (size_t)b * NFC * PIX;
    float acc[4][4];
#pragma unroll
    for (int i = 0; i < 4; i++)
#pragma unroll
        for (int j = 0; j < 4; j++) acc[i][j] = 0.f;

    for (int k0 = 0; k0 < K; k0 += 16) {
#pragma unroll
        for (int u = 0; u < 4; u++) {
            int idx = tid + 256 * u;
            int m = idx >> 4, kk = idx & 15;
            Ws[kk][m] = W[(size_t)(bm + m) * K + k0 + kk];
        }
#pragma unroll
        for (int u = 0; u < 4; u++) {
            int idx = tid + 256 * u;
            int n = idx & 63, kk = idx >> 6;
            int k = k0 + kk;
            int ic = k / 9;
            int t  = k - ic * 9;
            int dy = t / 3 - 1;
            int dx = t - (t / 3) * 3 - 1;
            int yy = y + dy, xx = n + dx;
            float v = 0.f;
            if (yy >= 0 && yy < IMGS && xx >= 0 && xx < IMGS)
                v = inb[((size_t)ic * IMGS + yy) * IMGS + xx];
            Xs[kk][n] = v;
        }
        __syncthreads();
#pragma unroll
        for (int kk = 0; kk < 16; kk++) {
            float4 av = *(const float4*)&Ws[kk][ty * 4];
            float4 bv = *(const float4*)&Xs[kk][tx * 4];
            acc[0][0] += av.x * bv.x; acc[0][1] += av.x * bv.y; acc[0][2] += av.x * bv.z; acc[0][3] += av.x * bv.w;
            acc[1][0] += av.y * bv.x; acc[1][1] += av.y * bv.y; acc[1][2] += av.y * bv.z; acc[1][3] += av.y * bv.w;
            acc[2][0] += av.z * bv.x; acc[2][1] += av.z * bv.y; acc[2][2] += av.z * bv.z; acc[2][3] += av.z * bv.w;
            acc[3][0] += av.w * bv.x; acc[3][1] += av.w * bv.y; acc[3][2] += av.w * bv.z; acc[3][3] += av.w * bv.w;
        }
        __syncthreads();
    }
#pragma unroll
    for (int i = 0; i < 4; i++) {
        int m = bm + ty * 4 + i;
        float bv = bias[m];
        float4 v = make_float4(acc[i][0] + bv, acc[i][1] + bv, acc[i][2] + bv, acc[i][3] + bv);
        size_t off = ((size_t)b * NFC + m) * PIX + bn + tx * 4;
        if (resid) {
            float4 o = *(const float4*)&resid[off];
            v.x += o.x; v.y += o.y; v.z += o.z; v.w += o.w;
        }
        if (relu) {
            v.x = fmaxf(v.x, 0.f); v.y = fmaxf(v.y, 0.f);
            v.z = fmaxf(v.z, 0.f); v.w = fmaxf(v.w, 0.f);
        }
        *(float4*)&outp[off] = v;
    }
}

// -------------------- final 3-channel image conv + clip --------------------
__global__ void img_kernel(const float* __restrict__ y, const float* __restrict__ W,
                           const float* __restrict__ bias, float* __restrict__ oimg,
                           float* __restrict__ oraw) {
    int b = blockIdx.y;
    int pix = blockIdx.x * 256 + threadIdx.x;
    int yy0 = pix >> 6, xx0 = pix & 63;
    float acc[3] = {bias[0], bias[1], bias[2]};
    for (int c = 0; c < NFC; c++) {
        const float* yp = y + ((size_t)b * NFC + c) * PIX;
#pragma unroll
        for (int tap = 0; tap < 9; tap++) {
            int dy = tap / 3 - 1, dx = tap % 3 - 1;
            int yy = yy0 + dy, xx = xx0 + dx;
            float v = (yy >= 0 && yy < IMGS && xx >= 0 && xx < IMGS) ? yp[yy * IMGS + xx] : 0.f;
#pragma unroll
            for (int o = 0; o < 3; o++) acc[o] += W[((size_t)o * NFC + c) * 9 + tap] * v;
        }
    }
#pragma unroll
    for (int o = 0; o < 3; o++) {
        size_t off = ((size_t)b * 3 + o) * PIX + pix;
        oraw[off] = acc[o];
        oimg[off] = fminf(fmaxf(acc[o], -1.f), 1.f);
    }
}

extern "C" void kernel_launch(void* const* d_in, const int* in_sizes, int n_in,
                              void* d_out, int out_size, void* d_ws, size_t ws_size,
                              hipStream_t stream) {
    const float* lat     = (const float*)d_in[0];
    const float* ca_init = (const float*)d_in[1];
    const float* leak    = (const float*)d_in[2];
    const float* hyper_w = (const float*)d_in[3];
    const float* hyper_b = (const float*)d_in[4];
    const float* res_w1  = (const float*)d_in[5];
    const float* res_b1  = (const float*)d_in[6];
    const float* res_w2  = (const float*)d_in[7];
    const float* res_b2  = (const float*)d_in[8];
    const float* img_w   = (const float*)d_in[9];
    const float* img_b   = (const float*)d_in[10];

    float* out      = (float*)d_out;
    float* out_img  = out;
    float* embs     = out + (size_t)BATCH * 3 * PIX;                  // 98304
    float* out_raw  = embs + (size_t)(NCALLS + 1) * BATCH * NFC * PIX;

    float* ws   = (float*)d_ws;
    float* kall = ws;
    float* p    = kall + (size_t)BATCH * KTOT;        // 1,579,008 floats
    float* h2   = p + (size_t)BATCH * FIN * PIX;      // +12,582,912
    // after the step loop, p's region is reused for the conv intermediates
    float* hres = p;
    float* ybuf = h2;

    hyper_kernel<<<KTOT / 256, 256, 0, stream>>>(lat, hyper_w, hyper_b, kall);

    int n4 = BATCH * NFC * PIX / 4;
    copy4_kernel<<<(n4 + 255) / 256, 256, 0, stream>>>((const float4*)ca_init, (float4*)embs, n4);

    const size_t stateN = (size_t)BATCH * NFC * PIX;
    for (int t = 0; t < NCALLS; t++) {
        const float* cur = embs + (size_t)t * stateN;
        float* nxt = embs + (size_t)(t + 1) * stateN;
        norm_kernel<<<dim3(NFC, BATCH), 256, 0, stream>>>(cur, p);
        fused_h_kernel<<<dim3(64, BATCH), 256, 0, stream>>>(kall, p, h2);
        fused_dn_kernel<<<dim3(64, 2, BATCH), 256, 0, stream>>>(kall, h2, p, cur, nxt, leak);
    }

    const float* fin = embs + (size_t)NCALLS * stateN;
    conv_gemm_kernel<<<dim3(64, 2, BATCH), 256, 0, stream>>>(fin,  res_w1, res_b1, nullptr, hres, 1);
    conv_gemm_kernel<<<dim3(64, 2, BATCH), 256, 0, stream>>>(hres, res_w2, res_b2, fin,     ybuf, 0);
    img_kernel<<<dim3(16, BATCH), 256, 0, stream>>>(ybuf, img_w, img_b, out_img, out_raw);
}